// Round 7
// baseline (1019.221 us; speedup 1.0000x reference)
//
#include <hip/hip_runtime.h>
#include <cstdint>
#include <cstddef>
#include <math.h>

// ---------------------------------------------------------------------------
// SturtGAT round 7: (a) revert rowid scatter (fill writes colv only — r6's
// 247MB write amplification), (b) dst-major edge-record kernel writes 16B
// (src,x0,x1) records sequentially, (c) aggr loads records + pipelines 4
// h-gathers in flight (was 2) — aggr is gather-latency-bound.
// ---------------------------------------------------------------------------

typedef __attribute__((ext_vector_type(8))) short short8;   // 8 bf16 (4 VGPRs)
typedef __attribute__((ext_vector_type(4))) float f32x4;    // 4 fp32 acc
typedef __attribute__((ext_vector_type(2))) float f32x2;    // packed fma pair

struct P3f { const float* p[3]; };
struct P3c { const int* p[3]; };

__device__ __forceinline__ float leakyf(float x) { return x > 0.f ? x : 0.2f * x; }
__device__ __forceinline__ float eluf(float x)   { return x > 0.f ? x : expm1f(x); }

__device__ __forceinline__ unsigned short bf16r(float x) {  // RNE fp32->bf16
  unsigned int u = __float_as_uint(x);
  u += 0x7fffu + ((u >> 16) & 1u);
  return (unsigned short)(u >> 16);
}
__device__ __forceinline__ float bflo(unsigned int u) { return __uint_as_float(u << 16); }
__device__ __forceinline__ float bfhi(unsigned int u) { return __uint_as_float(u & 0xffff0000u); }

// unpack 8 bf16 (uint4), packed-fma into a[0..3] (f32x2 each) with scalar xx
__device__ __forceinline__ void bf8_fma2(uint4 q, float xx, f32x2* a) {
  f32x2 v0 = {bflo(q.x), bfhi(q.x)};
  f32x2 v1 = {bflo(q.y), bfhi(q.y)};
  f32x2 v2 = {bflo(q.z), bfhi(q.z)};
  f32x2 v3 = {bflo(q.w), bfhi(q.w)};
  a[0] += xx * v0;
  a[1] += xx * v1;
  a[2] += xx * v2;
  a[3] += xx * v3;
}

// ---------------- utility ----------------
__global__ __launch_bounds__(256) void zero_int_kernel(int* p, int n) {
  int i = blockIdx.x * blockDim.x + threadIdx.x;
  if (i < n) p[i] = 0;
}

// ---------------- CSR build (batched over 3 orders) ----------------
__global__ __launch_bounds__(256) void count3_kernel(P3c adj, int* __restrict__ cntb,
                                                     int E, int N) {
  int i = blockIdx.x * blockDim.x + threadIdx.x;
  int o = blockIdx.y;
  if (i < E) atomicAdd(&cntb[o * N + adj.p[o][E + i]], 1);
}

#define SCAN_T 256
#define SCAN_VPT 8
#define SCAN_TILE 2048

__global__ __launch_bounds__(SCAN_T) void scan1_kernel(const int* __restrict__ cntb,
    int* __restrict__ rowptrb, int* __restrict__ bsums, int N) {
  __shared__ int lds[SCAN_T];
  const int o = blockIdx.y;
  const int* cnt = cntb + o * N;
  int* rowptr = rowptrb + o * (N + 1);
  int t = threadIdx.x;
  int base = blockIdx.x * SCAN_TILE + t * SCAN_VPT;
  int v[SCAN_VPT];
  int s = 0;
#pragma unroll
  for (int i = 0; i < SCAN_VPT; ++i) {
    int idx = base + i;
    int x = (idx < N) ? cnt[idx] : 0;
    s += x;
    v[i] = s;
  }
  lds[t] = s;
  __syncthreads();
  for (int off = 1; off < SCAN_T; off <<= 1) {
    int add = (t >= off) ? lds[t - off] : 0;
    __syncthreads();
    lds[t] += add;
    __syncthreads();
  }
  int excl = (t > 0) ? lds[t - 1] : 0;
#pragma unroll
  for (int i = 0; i < SCAN_VPT; ++i) {
    int idx = base + i;
    if (idx < N) rowptr[idx + 1] = excl + v[i];
  }
  if (t == SCAN_T - 1) bsums[o * 64 + blockIdx.x] = lds[t];
}

__global__ void scan2_kernel(int* bsums, int nb, int* rowptrb, int N) {
  if (threadIdx.x == 0 && blockIdx.x == 0) {
    for (int o = 0; o < 3; ++o) {
      int run = 0;
      for (int i = 0; i < nb; ++i) {
        int x = bsums[o * 64 + i];
        bsums[o * 64 + i] = run;
        run += x;
      }
      rowptrb[o * (N + 1)] = 0;
    }
  }
}

__global__ __launch_bounds__(256) void scan3_kernel(int* __restrict__ rowptrb,
    const int* __restrict__ bsums, int N) {
  int idx = blockIdx.x * blockDim.x + threadIdx.x;
  int o = blockIdx.y;
  if (idx < N) rowptrb[o * (N + 1) + idx + 1] += bsums[o * 64 + idx / SCAN_TILE];
}

__global__ __launch_bounds__(256) void fill3_kernel(P3c adj,
    const int* __restrict__ rowptrb, int* __restrict__ curb,
    int* __restrict__ colvb, int E, int N) {
  int i = blockIdx.x * blockDim.x + threadIdx.x;
  int o = blockIdx.y;
  if (i < E) {
    const int* a = adj.p[o];
    int d = a[E + i];
    int pos = atomicAdd(&curb[o * N + d], 1);
    colvb[(size_t)o * E + rowptrb[o * (N + 1) + d] + pos] = a[i];
  }
}

// ---------------- edge records (dst-major): rec = (src, x0, x1, 0) ----------------
// one thread per (node, order); sequential 16B writes per node range.
__global__ __launch_bounds__(256) void edge_rec_kernel(const int* __restrict__ colvb,
    const int* __restrict__ rowptrb, const float2* __restrict__ alsB,
    const float2* __restrict__ aldB, uint4* __restrict__ recB, int E, int N) {
  int n = blockIdx.x * blockDim.x + threadIdx.x;
  int o = blockIdx.y;
  if (n >= N) return;
  const float2 ad = aldB[(size_t)o * N + n];
  const float2* als = alsB + (size_t)o * N;
  const int* colv = colvb + (size_t)o * E;
  uint4* rec = recB + (size_t)o * E;
  int beg = rowptrb[o * (N + 1) + n], end = rowptrb[o * (N + 1) + n + 1];
  for (int j = beg; j < end; ++j) {
    int s = colv[j];
    float2 a = als[s];
    float x0 = __expf(leakyf(a.x + ad.x));
    float x1 = __expf(leakyf(a.y + ad.y));
    rec[j] = make_uint4((unsigned int)s, __float_as_uint(x0), __float_as_uint(x1), 0u);
  }
}

// ---------------- weight transpose+convert (batched) ----------------
__global__ __launch_bounds__(256) void conv_bt3_kernel(P3f W,
    unsigned short* __restrict__ BtB, int K, int NC, int Kpad) {
  int n = blockIdx.y;
  int o = blockIdx.z;
  int k = blockIdx.x * 256 + threadIdx.x;
  if (k >= Kpad) return;
  float v = (k < K) ? W.p[o][(size_t)k * NC + n] : 0.f;
  BtB[(size_t)o * NC * Kpad + (size_t)n * Kpad + k] = bf16r(v);
}

// ---------------- MFMA bf16 GEMM (batched over orders), bf16 h + fused al ----------------
#define GBM 128
#define LDSTRIDE 40

template<int NT, bool ABF16>
__global__ __launch_bounds__(256) void mfma_gemm_kernel(
    const void* __restrict__ Av, const unsigned short* __restrict__ BtB,
    P3f asp, P3f adp, unsigned short* __restrict__ CbB,
    float2* __restrict__ alsB, float2* __restrict__ aldB, int M, int K) {
  constexpr int NC = NT * 16;
  constexpr int CH = NT * 8;          // per-head channels
  __shared__ unsigned short As[GBM * LDSTRIDE];
  __shared__ unsigned short Bs[NC * LDSTRIDE];
  const int t = threadIdx.x;
  const int o = blockIdx.y;
  const int wave = t >> 6, lane = t & 63;
  const int quad = lane >> 4, l16 = lane & 15;
  const int m0 = blockIdx.x * GBM;
  const int Kpad = (K + 31) & ~31;
  const unsigned short* Bt = BtB + (size_t)o * NC * Kpad;
  unsigned short* Cb = CbB + (size_t)o * M * NC;
  float2* al_s = alsB + (size_t)o * M;
  float2* al_d = aldB + (size_t)o * M;
  const float* a_src = asp.p[o];
  const float* a_dst = adp.p[o];

  f32x4 acc[2][NT];
#pragma unroll
  for (int i = 0; i < 2; ++i)
#pragma unroll
    for (int j = 0; j < NT; ++j) acc[i][j] = (f32x4){0.f, 0.f, 0.f, 0.f};

  const int arow = t >> 1;
  const int akoff = (t & 1) * 16;
  const int gm = m0 + arow;
  const unsigned short* browp = Bt + (size_t)arow * Kpad;

  for (int k0 = 0; k0 < Kpad; k0 += 32) {
    if (k0) __syncthreads();
    const int kb = k0 + akoff;
    if constexpr (ABF16) {
      const unsigned short* arowp = (const unsigned short*)Av + (size_t)gm * K;
      uint4 q0 = {0, 0, 0, 0}, q1 = {0, 0, 0, 0};
      if (gm < M) {
        const uint4* p = (const uint4*)(arowp + kb);   // K == Kpad for bf16 path
        q0 = p[0]; q1 = p[1];
      }
      short8* dst = (short8*)&As[arow * LDSTRIDE + akoff];
      union { uint4 q; short8 s; } c0, c1;
      c0.q = q0; c1.q = q1;
      dst[0] = c0.s;
      dst[1] = c1.s;
    } else {
      const float* arowp = (const float*)Av + (size_t)gm * K;
      float v[16];
      if (gm < M && kb + 16 <= K) {
        const float4* p = (const float4*)(arowp + kb);
#pragma unroll
        for (int i = 0; i < 4; ++i) {
          float4 q = p[i];
          v[4 * i] = q.x; v[4 * i + 1] = q.y; v[4 * i + 2] = q.z; v[4 * i + 3] = q.w;
        }
      } else {
#pragma unroll
        for (int i = 0; i < 16; ++i)
          v[i] = (gm < M && kb + i < K) ? arowp[kb + i] : 0.f;
      }
      union { unsigned short u[16]; short8 s[2]; } pk;
#pragma unroll
      for (int i = 0; i < 16; ++i) pk.u[i] = bf16r(v[i]);
      short8* dst = (short8*)&As[arow * LDSTRIDE + akoff];
      dst[0] = pk.s[0];
      dst[1] = pk.s[1];
    }
    if (arow < NC) {
      const uint4* p = (const uint4*)(browp + k0 + akoff);
      uint4 q0 = p[0], q1 = p[1];
      short8* dst = (short8*)&Bs[arow * LDSTRIDE + akoff];
      union { uint4 q; short8 s; } c0, c1;
      c0.q = q0; c1.q = q1;
      dst[0] = c0.s;
      dst[1] = c1.s;
    }
    __syncthreads();
    short8 af[2];
#pragma unroll
    for (int rt = 0; rt < 2; ++rt)
      af[rt] = *(const short8*)&As[(wave * 32 + rt * 16 + l16) * LDSTRIDE + quad * 8];
    short8 bfv[NT];
#pragma unroll
    for (int ct = 0; ct < NT; ++ct)
      bfv[ct] = *(const short8*)&Bs[(ct * 16 + l16) * LDSTRIDE + quad * 8];
#pragma unroll
    for (int rt = 0; rt < 2; ++rt)
#pragma unroll
      for (int ct = 0; ct < NT; ++ct)
        acc[rt][ct] = __builtin_amdgcn_mfma_f32_16x16x32_bf16(af[rt], bfv[ct],
                                                              acc[rt][ct], 0, 0, 0);
  }
  // ---- epilogue: bf16 h store + fused al_s/al_d ----
  float asv[NT], adv[NT];
#pragma unroll
  for (int ct = 0; ct < NT; ++ct) {
    int col = ct * 16 + l16;
    asv[ct] = a_src[col];
    adv[ct] = a_dst[col];
  }
#pragma unroll
  for (int rt = 0; rt < 2; ++rt) {
    int gr0 = m0 + wave * 32 + rt * 16 + quad * 4;
#pragma unroll
    for (int r = 0; r < 4; ++r) {
      int gr = gr0 + r;
      float ps0 = 0.f, ps1 = 0.f, pd0 = 0.f, pd1 = 0.f;
#pragma unroll
      for (int ct = 0; ct < NT; ++ct) {
        int col = ct * 16 + l16;
        float v = acc[rt][ct][r];
        if (gr < M) Cb[(size_t)gr * NC + col] = bf16r(v);
        if (col < CH) { ps0 += v * asv[ct]; pd0 += v * adv[ct]; }
        else          { ps1 += v * asv[ct]; pd1 += v * adv[ct]; }
      }
#pragma unroll
      for (int off = 1; off < 16; off <<= 1) {
        ps0 += __shfl_xor(ps0, off, 64);
        ps1 += __shfl_xor(ps1, off, 64);
        pd0 += __shfl_xor(pd0, off, 64);
        pd1 += __shfl_xor(pd1, off, 64);
      }
      if (l16 == 0 && gr < M) {
        al_s[gr] = make_float2(ps0, ps1);
        al_d[gr] = make_float2(pd0, pd1);
      }
    }
  }
}

// ---------------- GAT aggregate v6: record loads + 4-deep gather pipeline ----------------
// One wave per (dst node, order). bf16 h gathers, bf16 state output.
template<int C, int CONCAT>
__global__ __launch_bounds__(256) void gat_aggr6_kernel(
    const unsigned short* __restrict__ hB, const float2* __restrict__ alsB,
    const float2* __restrict__ aldB, const int* __restrict__ rowptrB,
    const uint4* __restrict__ recB, P3f biasp, unsigned short* __restrict__ outB,
    int N, int E) {
  constexpr int HC = 2 * C;
  constexpr int FL = HC / 8;        // lanes per edge slot: 16 (C=64) or 10 (C=40)
  constexpr int ES = 64 / FL;       // edge slots: 4 or 6
  constexpr int HB = C / 8;         // head boundary in lane units (8, 5)
  constexpr int OW = CONCAT ? HC : C;
  const int o = blockIdx.y;
  const unsigned short* h = hB + (size_t)o * N * HC;
  const float2* al_s = alsB + (size_t)o * N;
  const float2* al_d = aldB + (size_t)o * N;
  const int* rowptr = rowptrB + o * (N + 1);
  const float* bias = biasp.p[o];
  unsigned short* out = outB + (size_t)o * N * OW;

  int w = (blockIdx.x * blockDim.x + threadIdx.x) >> 6;
  int lane = threadIdx.x & 63;
  if (w >= N) return;
  const int eslot = lane / FL;
  const int f4 = lane - eslot * FL;
  const bool glane = lane < ES * FL;
  const float2 ad = al_d[w];
  const float2 asf = al_s[w];
  const int beg = rowptr[w], end = rowptr[w + 1];
  const int deg = end - beg;
  const uint4* rp = recB + (size_t)o * E + beg;

  // no max subtraction: logits are O(1) here, softmax is shift-invariant.
  const float xs0 = __expf(leakyf(asf.x + ad.x));
  const float xs1 = __expf(leakyf(asf.y + ad.y));

  f32x2 acc[4] = {}, acc2[4] = {};
  float dp0 = 0.f, dp1 = 0.f;

  // 4 rounds per iteration: all record loads issue, then all h gathers,
  // then the FMAs — 4 gathers in flight per lane.
  for (int jj = 0; jj < deg; jj += 4 * ES) {
    int j0 = jj + eslot, j1 = jj + ES + eslot, j2 = jj + 2 * ES + eslot,
        j3 = jj + 3 * ES + eslot;
    bool v0 = glane && j0 < deg, v1 = glane && j1 < deg,
         v2 = glane && j2 < deg, v3 = glane && j3 < deg;
    uint4 r0, r1, r2, r3;
    if (v0) r0 = rp[j0];
    if (v1) r1 = rp[j1];
    if (v2) r2 = rp[j2];
    if (v3) r3 = rp[j3];
    uint4 q0, q1, q2, q3;
    if (v0) q0 = ((const uint4*)(h + (size_t)r0.x * HC))[f4];
    if (v1) q1 = ((const uint4*)(h + (size_t)r1.x * HC))[f4];
    if (v2) q2 = ((const uint4*)(h + (size_t)r2.x * HC))[f4];
    if (v3) q3 = ((const uint4*)(h + (size_t)r3.x * HC))[f4];
    if (v0) {
      float x0 = __uint_as_float(r0.y), x1 = __uint_as_float(r0.z);
      if (f4 == 0) { dp0 += x0; dp1 += x1; }
      bf8_fma2(q0, (f4 < HB) ? x0 : x1, acc);
    }
    if (v1) {
      float x0 = __uint_as_float(r1.y), x1 = __uint_as_float(r1.z);
      if (f4 == 0) { dp0 += x0; dp1 += x1; }
      bf8_fma2(q1, (f4 < HB) ? x0 : x1, acc2);
    }
    if (v2) {
      float x0 = __uint_as_float(r2.y), x1 = __uint_as_float(r2.z);
      if (f4 == 0) { dp0 += x0; dp1 += x1; }
      bf8_fma2(q2, (f4 < HB) ? x0 : x1, acc);
    }
    if (v3) {
      float x0 = __uint_as_float(r3.y), x1 = __uint_as_float(r3.z);
      if (f4 == 0) { dp0 += x0; dp1 += x1; }
      bf8_fma2(q3, (f4 < HB) ? x0 : x1, acc2);
    }
  }

  // denominators (dp nonzero only on f4==0 lanes)
#pragma unroll
  for (int off = 1; off < 64; off <<= 1) {
    dp0 += __shfl_xor(dp0, off, 64);
    dp1 += __shfl_xor(dp1, off, 64);
  }
  float den0 = dp0 + xs0, den1 = dp1 + xs1;

  // self-loop message (slot 0 lanes)
  if (eslot == 0) {
    uint4 q = ((const uint4*)(h + (size_t)w * HC))[f4];
    bf8_fma2(q, (f4 < HB) ? xs0 : xs1, acc);
  }
#pragma unroll
  for (int i = 0; i < 4; ++i) acc[i] += acc2[i];

  // slot folds: sum per-slot partials into slot 0 (lanes < FL)
  auto fold = [&](int off, int lim) {
#pragma unroll
    for (int i = 0; i < 4; ++i) {
      float t0 = __shfl(acc[i][0], lane + off, 64);
      float t1 = __shfl(acc[i][1], lane + off, 64);
      if (lane < lim) { acc[i][0] += t0; acc[i][1] += t1; }
    }
  };
  if (ES == 4) {
    fold(2 * FL, 2 * FL);
    fold(FL, FL);
  } else {                 // ES == 6
    fold(3 * FL, 3 * FL);  // slots 0..2 += slots 3..5
    fold(FL, FL);          // slot 0 += slot 1
    fold(2 * FL, FL);      // slot 0 += slot 2
  }

  float inv0 = 1.f / (den0 + 1e-16f), inv1 = 1.f / (den1 + 1e-16f);
  if (CONCAT) {
    if (lane < FL) {
      float xx = (f4 < HB) ? inv0 : inv1;
      const float* bp = bias + f4 * 8;
      unsigned int pk[4];
#pragma unroll
      for (int i = 0; i < 4; ++i) {
        unsigned short lo = bf16r(eluf(acc[i][0] * xx + bp[2 * i]));
        unsigned short hi = bf16r(eluf(acc[i][1] * xx + bp[2 * i + 1]));
        pk[i] = (unsigned int)lo | ((unsigned int)hi << 16);
      }
      ((uint4*)(out + (size_t)w * OW + f4 * 8))[0] = make_uint4(pk[0], pk[1], pk[2], pk[3]);
    }
  } else {
    float p[8];
#pragma unroll
    for (int i = 0; i < 4; ++i) {
      p[2 * i]     = __shfl(acc[i][0], lane + HB, 64);
      p[2 * i + 1] = __shfl(acc[i][1], lane + HB, 64);
    }
    if (lane < HB) {
      const float* bp = bias + f4 * 8;
      unsigned int pk[4];
#pragma unroll
      for (int i = 0; i < 4; ++i) {
        float v0 = 0.5f * (acc[i][0] * inv0 + p[2 * i] * inv1) + bp[2 * i];
        float v1 = 0.5f * (acc[i][1] * inv0 + p[2 * i + 1] * inv1) + bp[2 * i + 1];
        pk[i] = (unsigned int)bf16r(eluf(v0)) | ((unsigned int)bf16r(eluf(v1)) << 16);
      }
      ((uint4*)(out + (size_t)w * OW + f4 * 8))[0] = make_uint4(pk[0], pk[1], pk[2], pk[3]);
    }
  }
}

// ---------------- order-mix (bf16 states in; bf16 or fp32 out) ----------------
template<int BF16OUT>
__global__ __launch_bounds__(256) void mixb_kernel(const unsigned short* __restrict__ sb,
    const float* __restrict__ Wm, const float* __restrict__ wf,
    void* __restrict__ out, int perU) {
  int i = blockIdx.x * blockDim.x + threadIdx.x;
  if (i >= perU) return;
  const unsigned int* sp = (const unsigned int*)sb;
  unsigned int u0 = sp[i];
  unsigned int u1 = sp[perU + i];
  unsigned int u2 = sp[2 * perU + i];
  float a0 = bflo(u0), a1 = bfhi(u0);
  float b0 = bflo(u1), b1 = bfhi(u1);
  float c0 = bflo(u2), c1 = bfhi(u2);
  float r0 = 0.f, r1 = 0.f;
#pragma unroll
  for (int j = 0; j < 3; ++j) {
    float w0 = Wm[j], w1 = Wm[3 + j], w2 = Wm[6 + j], wj = wf[j];
    r0 += wj * eluf(a0 * w0 + b0 * w1 + c0 * w2);
    r1 += wj * eluf(a1 * w0 + b1 * w1 + c1 * w2);
  }
  if (BF16OUT) {
    ((unsigned int*)out)[i] = (unsigned int)bf16r(r0) | ((unsigned int)bf16r(r1) << 16);
  } else {
    ((float2*)out)[i] = make_float2(r0, r1);
  }
}

// ---------------- log_softmax ----------------
__global__ __launch_bounds__(256) void log_softmax_kernel(const float* __restrict__ x,
    float* __restrict__ out, int N, int C) {
  int w = (blockIdx.x * blockDim.x + threadIdx.x) >> 6;
  int lane = threadIdx.x & 63;
  if (w >= N) return;
  float v = (lane < C) ? x[(size_t)w * C + lane] : -INFINITY;
  float mx = v;
#pragma unroll
  for (int off = 1; off < 64; off <<= 1) mx = fmaxf(mx, __shfl_xor(mx, off, 64));
  float ex = (lane < C) ? expf(v - mx) : 0.f;
  float s = ex;
#pragma unroll
  for (int off = 1; off < 64; off <<= 1) s += __shfl_xor(s, off, 64);
  if (lane < C) out[(size_t)w * C + lane] = v - mx - logf(s);
}

// ---------------------------------------------------------------------------
extern "C" void kernel_launch(void* const* d_in, const int* in_sizes, int n_in,
                              void* d_out, int out_size, void* d_ws, size_t ws_size,
                              hipStream_t stream) {
  const int F_IN = 500;
  const int N = in_sizes[0] / F_IN;     // 50000
  const int E = in_sizes[1] / 2;        // 800000
  const int HC0 = 128;
  const int HC1 = 80;
  const int C1 = 40;
  const int K0pad = 512, K1pad = 128;

  const float* x0 = (const float*)d_in[0];
  P3c adj;
  adj.p[0] = (const int*)d_in[1];
  adj.p[1] = (const int*)d_in[2];
  adj.p[2] = (const int*)d_in[3];
  P3f W0p, as0p, ad0p, b0p, W1p, as1p, ad1p, b1p;
  for (int o = 0; o < 3; ++o) {
    W0p.p[o]  = (const float*)d_in[4 + 4 * o + 0];
    as0p.p[o] = (const float*)d_in[4 + 4 * o + 1];
    ad0p.p[o] = (const float*)d_in[4 + 4 * o + 2];
    b0p.p[o]  = (const float*)d_in[4 + 4 * o + 3];
    W1p.p[o]  = (const float*)d_in[16 + 4 * o + 0];
    as1p.p[o] = (const float*)d_in[16 + 4 * o + 1];
    ad1p.p[o] = (const float*)d_in[16 + 4 * o + 2];
    b1p.p[o]  = (const float*)d_in[16 + 4 * o + 3];
  }
  const float* agg0W = (const float*)d_in[28];
  const float* agg0w = (const float*)d_in[29];
  const float* agg1W = (const float*)d_in[30];
  const float* agg1w = (const float*)d_in[31];

  // ---- workspace layout ----
  char* ws = (char*)d_ws;
  size_t off = 0;
  auto alloc = [&](size_t bytes) -> void* {
    off = (off + 255) & ~(size_t)255;
    void* p = ws + off;
    off += bytes;
    return p;
  };
  int* rowptrb = (int*)alloc((size_t)3 * (N + 1) * 4);
  int* colvb   = (int*)alloc((size_t)3 * E * 4);
  int* cntcur  = (int*)alloc((size_t)6 * N * 4);   // cnt[3N] then cur[3N]
  int* bsums   = (int*)alloc(3 * 64 * 4);
  unsigned short* hB  = (unsigned short*)alloc((size_t)3 * N * HC0 * 2);  // bf16 h
  unsigned short* stB = (unsigned short*)alloc((size_t)3 * N * HC0 * 2);  // bf16 states; block0 reused as bf16 x1
  float* x2 = (float*)alloc((size_t)N * C1 * 4);
  float2* alsB = (float2*)alloc((size_t)3 * N * 8);
  float2* aldB = (float2*)alloc((size_t)3 * N * 8);
  uint4* recB  = (uint4*)alloc((size_t)3 * E * 16);                       // edge records
  unsigned short* Bt0B = (unsigned short*)alloc((size_t)3 * HC0 * K0pad * 2);
  unsigned short* Bt1B = (unsigned short*)alloc((size_t)3 * HC1 * K1pad * 2);
  (void)ws_size;

  const int TB = 256;
  const int nbE = (E + TB - 1) / TB;
  const int nbN = (N + TB - 1) / TB;
  const int scanBlocks = (N + SCAN_TILE - 1) / SCAN_TILE;
  const int waveBlocks = (int)(((size_t)N * 64 + TB - 1) / TB);
  const int gemmBlocks = (N + GBM - 1) / GBM;

  // ---- weight conversion ----
  conv_bt3_kernel<<<dim3((K0pad + 255) / 256, HC0, 3), TB, 0, stream>>>(W0p, Bt0B, F_IN, HC0, K0pad);
  conv_bt3_kernel<<<dim3((K1pad + 255) / 256, HC1, 3), TB, 0, stream>>>(W1p, Bt1B, HC0, HC1, K1pad);

  // ---- CSR, all 3 orders ----
  zero_int_kernel<<<(6 * N + TB - 1) / TB, TB, 0, stream>>>(cntcur, 6 * N);
  count3_kernel<<<dim3(nbE, 3), TB, 0, stream>>>(adj, cntcur, E, N);
  scan1_kernel<<<dim3(scanBlocks, 3), SCAN_T, 0, stream>>>(cntcur, rowptrb, bsums, N);
  scan2_kernel<<<1, 64, 0, stream>>>(bsums, scanBlocks, rowptrb, N);
  scan3_kernel<<<dim3(nbN, 3), TB, 0, stream>>>(rowptrb, bsums, N);
  fill3_kernel<<<dim3(nbE, 3), TB, 0, stream>>>(adj, rowptrb, cntcur + 3 * N, colvb, E, N);

  // ---- layer 0 (concat) ----
  mfma_gemm_kernel<8, false><<<dim3(gemmBlocks, 3), TB, 0, stream>>>(
      x0, Bt0B, as0p, ad0p, hB, alsB, aldB, N, F_IN);
  edge_rec_kernel<<<dim3(nbN, 3), TB, 0, stream>>>(colvb, rowptrb, alsB, aldB, recB, E, N);
  gat_aggr6_kernel<64, 1><<<dim3(waveBlocks, 3), TB, 0, stream>>>(
      hB, alsB, aldB, rowptrb, recB, b0p, stB, N, E);
  mixb_kernel<1><<<((N * HC0 / 2) + TB - 1) / TB, TB, 0, stream>>>(
      stB, agg0W, agg0w, stB, N * HC0 / 2);   // in-place bf16 x1 over state block 0

  // ---- layer 1 (mean over heads) ----
  mfma_gemm_kernel<5, true><<<dim3(gemmBlocks, 3), TB, 0, stream>>>(
      stB, Bt1B, as1p, ad1p, hB, alsB, aldB, N, HC0);
  edge_rec_kernel<<<dim3(nbN, 3), TB, 0, stream>>>(colvb, rowptrb, alsB, aldB, recB, E, N);
  gat_aggr6_kernel<40, 0><<<dim3(waveBlocks, 3), TB, 0, stream>>>(
      hB, alsB, aldB, rowptrb, recB, b1p, stB, N, E);
  mixb_kernel<0><<<((N * C1 / 2) + TB - 1) / TB, TB, 0, stream>>>(
      stB, agg1W, agg1w, x2, N * C1 / 2);

  log_softmax_kernel<<<waveBlocks, TB, 0, stream>>>(x2, (float*)d_out, N, C1);
}

// Round 8
// 854.234 us; speedup vs baseline: 1.1931x; 1.1931x over previous
//
#include <hip/hip_runtime.h>
#include <cstdint>
#include <cstddef>
#include <math.h>

// ---------------------------------------------------------------------------
// SturtGAT round 8: consolidate. Aggregation reverted to R5's aggr4 structure
// (measured best: shuffle broadcast + 1-deep h-gather chain), widened to 4
// gather steps/iter. x0 pre-converted to bf16 once -> layer-0 GEMM uses the
// bf16-A staging path (no per-tile cvt, half the A bytes). fill writes colv
// only (R6's rowid write-amplification lesson).
// ---------------------------------------------------------------------------

typedef __attribute__((ext_vector_type(8))) short short8;   // 8 bf16 (4 VGPRs)
typedef __attribute__((ext_vector_type(4))) float f32x4;    // 4 fp32 acc
typedef __attribute__((ext_vector_type(2))) float f32x2;    // packed fma pair

struct P3f { const float* p[3]; };
struct P3c { const int* p[3]; };

__device__ __forceinline__ float leakyf(float x) { return x > 0.f ? x : 0.2f * x; }
__device__ __forceinline__ float eluf(float x)   { return x > 0.f ? x : expm1f(x); }

__device__ __forceinline__ unsigned short bf16r(float x) {  // RNE fp32->bf16
  unsigned int u = __float_as_uint(x);
  u += 0x7fffu + ((u >> 16) & 1u);
  return (unsigned short)(u >> 16);
}
__device__ __forceinline__ float bflo(unsigned int u) { return __uint_as_float(u << 16); }
__device__ __forceinline__ float bfhi(unsigned int u) { return __uint_as_float(u & 0xffff0000u); }

// unpack 8 bf16 (uint4), packed-fma into a[0..3] (f32x2 each) with scalar xx
__device__ __forceinline__ void bf8_fma2(uint4 q, float xx, f32x2* a) {
  f32x2 v0 = {bflo(q.x), bfhi(q.x)};
  f32x2 v1 = {bflo(q.y), bfhi(q.y)};
  f32x2 v2 = {bflo(q.z), bfhi(q.z)};
  f32x2 v3 = {bflo(q.w), bfhi(q.w)};
  a[0] += xx * v0;
  a[1] += xx * v1;
  a[2] += xx * v2;
  a[3] += xx * v3;
}

// ---------------- utility ----------------
__global__ __launch_bounds__(256) void zero_int_kernel(int* p, int n) {
  int i = blockIdx.x * blockDim.x + threadIdx.x;
  if (i < n) p[i] = 0;
}

// ---------------- x0 fp32 -> bf16 (padded to K0pad) ----------------
__global__ __launch_bounds__(256) void convA_kernel(const float* __restrict__ A,
    unsigned short* __restrict__ Ab, int M, int K, int Kpad) {
  int i = blockIdx.x * blockDim.x + threadIdx.x;           // one per 8 outputs
  int row = i >> 6;                                        // Kpad/8 = 64 chunks
  int koff = (i & 63) * 8;
  if (row >= M) return;
  const float* ap = A + (size_t)row * K;
  unsigned short v[8];
  if (koff + 8 <= K) {
    float4 q0 = ((const float4*)(ap + koff))[0];
    float4 q1 = ((const float4*)(ap + koff))[1];
    v[0] = bf16r(q0.x); v[1] = bf16r(q0.y); v[2] = bf16r(q0.z); v[3] = bf16r(q0.w);
    v[4] = bf16r(q1.x); v[5] = bf16r(q1.y); v[6] = bf16r(q1.z); v[7] = bf16r(q1.w);
  } else {
#pragma unroll
    for (int k = 0; k < 8; ++k)
      v[k] = (koff + k < K) ? bf16r(ap[koff + k]) : (unsigned short)0;
  }
  *(uint4*)(Ab + (size_t)row * Kpad + koff) = *(const uint4*)v;
}

// ---------------- CSR build (batched over 3 orders) ----------------
__global__ __launch_bounds__(256) void count3_kernel(P3c adj, int* __restrict__ cntb,
                                                     int E, int N) {
  int i = blockIdx.x * blockDim.x + threadIdx.x;
  int o = blockIdx.y;
  if (i < E) atomicAdd(&cntb[o * N + adj.p[o][E + i]], 1);
}

#define SCAN_T 256
#define SCAN_VPT 8
#define SCAN_TILE 2048

__global__ __launch_bounds__(SCAN_T) void scan1_kernel(const int* __restrict__ cntb,
    int* __restrict__ rowptrb, int* __restrict__ bsums, int N) {
  __shared__ int lds[SCAN_T];
  const int o = blockIdx.y;
  const int* cnt = cntb + o * N;
  int* rowptr = rowptrb + o * (N + 1);
  int t = threadIdx.x;
  int base = blockIdx.x * SCAN_TILE + t * SCAN_VPT;
  int v[SCAN_VPT];
  int s = 0;
#pragma unroll
  for (int i = 0; i < SCAN_VPT; ++i) {
    int idx = base + i;
    int x = (idx < N) ? cnt[idx] : 0;
    s += x;
    v[i] = s;
  }
  lds[t] = s;
  __syncthreads();
  for (int off = 1; off < SCAN_T; off <<= 1) {
    int add = (t >= off) ? lds[t - off] : 0;
    __syncthreads();
    lds[t] += add;
    __syncthreads();
  }
  int excl = (t > 0) ? lds[t - 1] : 0;
#pragma unroll
  for (int i = 0; i < SCAN_VPT; ++i) {
    int idx = base + i;
    if (idx < N) rowptr[idx + 1] = excl + v[i];
  }
  if (t == SCAN_T - 1) bsums[o * 64 + blockIdx.x] = lds[t];
}

__global__ void scan2_kernel(int* bsums, int nb, int* rowptrb, int N) {
  if (threadIdx.x == 0 && blockIdx.x == 0) {
    for (int o = 0; o < 3; ++o) {
      int run = 0;
      for (int i = 0; i < nb; ++i) {
        int x = bsums[o * 64 + i];
        bsums[o * 64 + i] = run;
        run += x;
      }
      rowptrb[o * (N + 1)] = 0;
    }
  }
}

__global__ __launch_bounds__(256) void scan3_kernel(int* __restrict__ rowptrb,
    const int* __restrict__ bsums, int N) {
  int idx = blockIdx.x * blockDim.x + threadIdx.x;
  int o = blockIdx.y;
  if (idx < N) rowptrb[o * (N + 1) + idx + 1] += bsums[o * 64 + idx / SCAN_TILE];
}

__global__ __launch_bounds__(256) void fill3_kernel(P3c adj,
    const int* __restrict__ rowptrb, int* __restrict__ curb,
    int* __restrict__ colvb, int E, int N) {
  int i = blockIdx.x * blockDim.x + threadIdx.x;
  int o = blockIdx.y;
  if (i < E) {
    const int* a = adj.p[o];
    int d = a[E + i];
    int pos = atomicAdd(&curb[o * N + d], 1);
    colvb[(size_t)o * E + rowptrb[o * (N + 1) + d] + pos] = a[i];
  }
}

// ---------------- weight transpose+convert (batched) ----------------
__global__ __launch_bounds__(256) void conv_bt3_kernel(P3f W,
    unsigned short* __restrict__ BtB, int K, int NC, int Kpad) {
  int n = blockIdx.y;
  int o = blockIdx.z;
  int k = blockIdx.x * 256 + threadIdx.x;
  if (k >= Kpad) return;
  float v = (k < K) ? W.p[o][(size_t)k * NC + n] : 0.f;
  BtB[(size_t)o * NC * Kpad + (size_t)n * Kpad + k] = bf16r(v);
}

// ---------------- MFMA bf16 GEMM (batched over orders), bf16 A, bf16 h + fused al ----------------
#define GBM 128
#define LDSTRIDE 40

template<int NT>
__global__ __launch_bounds__(256) void mfma_gemm_kernel(
    const unsigned short* __restrict__ Ab, const unsigned short* __restrict__ BtB,
    P3f asp, P3f adp, unsigned short* __restrict__ CbB,
    float2* __restrict__ alsB, float2* __restrict__ aldB, int M, int Kpad) {
  constexpr int NC = NT * 16;
  constexpr int CH = NT * 8;          // per-head channels
  __shared__ unsigned short As[GBM * LDSTRIDE];
  __shared__ unsigned short Bs[NC * LDSTRIDE];
  const int t = threadIdx.x;
  const int o = blockIdx.y;
  const int wave = t >> 6, lane = t & 63;
  const int quad = lane >> 4, l16 = lane & 15;
  const int m0 = blockIdx.x * GBM;
  const unsigned short* Bt = BtB + (size_t)o * NC * Kpad;
  unsigned short* Cb = CbB + (size_t)o * M * NC;
  float2* al_s = alsB + (size_t)o * M;
  float2* al_d = aldB + (size_t)o * M;
  const float* a_src = asp.p[o];
  const float* a_dst = adp.p[o];

  f32x4 acc[2][NT];
#pragma unroll
  for (int i = 0; i < 2; ++i)
#pragma unroll
    for (int j = 0; j < NT; ++j) acc[i][j] = (f32x4){0.f, 0.f, 0.f, 0.f};

  const int arow = t >> 1;
  const int akoff = (t & 1) * 16;
  const int gm = m0 + arow;
  const unsigned short* arowp = Ab + (size_t)gm * Kpad;
  const unsigned short* browp = Bt + (size_t)arow * Kpad;

  for (int k0 = 0; k0 < Kpad; k0 += 32) {
    if (k0) __syncthreads();
    const int kb = k0 + akoff;
    {
      uint4 q0 = {0, 0, 0, 0}, q1 = {0, 0, 0, 0};
      if (gm < M) {
        const uint4* p = (const uint4*)(arowp + kb);
        q0 = p[0]; q1 = p[1];
      }
      short8* dst = (short8*)&As[arow * LDSTRIDE + akoff];
      union { uint4 q; short8 s; } c0, c1;
      c0.q = q0; c1.q = q1;
      dst[0] = c0.s;
      dst[1] = c1.s;
    }
    if (arow < NC) {
      const uint4* p = (const uint4*)(browp + kb);
      uint4 q0 = p[0], q1 = p[1];
      short8* dst = (short8*)&Bs[arow * LDSTRIDE + akoff];
      union { uint4 q; short8 s; } c0, c1;
      c0.q = q0; c1.q = q1;
      dst[0] = c0.s;
      dst[1] = c1.s;
    }
    __syncthreads();
    short8 af[2];
#pragma unroll
    for (int rt = 0; rt < 2; ++rt)
      af[rt] = *(const short8*)&As[(wave * 32 + rt * 16 + l16) * LDSTRIDE + quad * 8];
    short8 bfv[NT];
#pragma unroll
    for (int ct = 0; ct < NT; ++ct)
      bfv[ct] = *(const short8*)&Bs[(ct * 16 + l16) * LDSTRIDE + quad * 8];
#pragma unroll
    for (int rt = 0; rt < 2; ++rt)
#pragma unroll
      for (int ct = 0; ct < NT; ++ct)
        acc[rt][ct] = __builtin_amdgcn_mfma_f32_16x16x32_bf16(af[rt], bfv[ct],
                                                              acc[rt][ct], 0, 0, 0);
  }
  // ---- epilogue: bf16 h store + fused al_s/al_d ----
  float asv[NT], adv[NT];
#pragma unroll
  for (int ct = 0; ct < NT; ++ct) {
    int col = ct * 16 + l16;
    asv[ct] = a_src[col];
    adv[ct] = a_dst[col];
  }
#pragma unroll
  for (int rt = 0; rt < 2; ++rt) {
    int gr0 = m0 + wave * 32 + rt * 16 + quad * 4;
#pragma unroll
    for (int r = 0; r < 4; ++r) {
      int gr = gr0 + r;
      float ps0 = 0.f, ps1 = 0.f, pd0 = 0.f, pd1 = 0.f;
#pragma unroll
      for (int ct = 0; ct < NT; ++ct) {
        int col = ct * 16 + l16;
        float v = acc[rt][ct][r];
        if (gr < M) Cb[(size_t)gr * NC + col] = bf16r(v);
        if (col < CH) { ps0 += v * asv[ct]; pd0 += v * adv[ct]; }
        else          { ps1 += v * asv[ct]; pd1 += v * adv[ct]; }
      }
#pragma unroll
      for (int off = 1; off < 16; off <<= 1) {
        ps0 += __shfl_xor(ps0, off, 64);
        ps1 += __shfl_xor(ps1, off, 64);
        pd0 += __shfl_xor(pd0, off, 64);
        pd1 += __shfl_xor(pd1, off, 64);
      }
      if (l16 == 0 && gr < M) {
        al_s[gr] = make_float2(ps0, ps1);
        al_d[gr] = make_float2(pd0, pd1);
      }
    }
  }
}

// ---------------- GAT softmax+aggregate (R5 aggr4 structure, 4-step gather) ----------------
// One wave per (dst node, order). bf16 h gathers, bf16 state output.
template<int C, int CONCAT>
__global__ __launch_bounds__(256) void gat_aggr4_kernel(
    const unsigned short* __restrict__ hB, const float2* __restrict__ alsB,
    const float2* __restrict__ aldB, const int* __restrict__ rowptrB,
    const int* __restrict__ colvB, P3f biasp, unsigned short* __restrict__ outB,
    int N, int E) {
  constexpr int HC = 2 * C;
  constexpr int FL = HC / 8;        // lanes per edge slot: 16 (C=64) or 10 (C=40)
  constexpr int ES = 64 / FL;       // edge slots: 4 or 6
  constexpr int HB = C / 8;         // head boundary in lane units (8, 5)
  constexpr int OW = CONCAT ? HC : C;
  const int o = blockIdx.y;
  const unsigned short* h = hB + (size_t)o * N * HC;
  const float2* al_s = alsB + (size_t)o * N;
  const float2* al_d = aldB + (size_t)o * N;
  const int* rowptr = rowptrB + o * (N + 1);
  const float* bias = biasp.p[o];
  unsigned short* out = outB + (size_t)o * N * OW;

  int w = (blockIdx.x * blockDim.x + threadIdx.x) >> 6;
  int lane = threadIdx.x & 63;
  if (w >= N) return;
  const int eslot = lane / FL;
  const int f4 = lane - eslot * FL;
  const bool glane = lane < ES * FL;
  const float2 ad = al_d[w];
  const float2 asf = al_s[w];
  const int beg = rowptr[w], end = rowptr[w + 1];
  const int deg = end - beg;
  const int* colv = colvB + (size_t)o * E;

  // no max subtraction: logits are O(1) here, softmax is shift-invariant.
  const float xs0 = __expf(leakyf(asf.x + ad.x));
  const float xs1 = __expf(leakyf(asf.y + ad.y));

  f32x2 acc[4] = {}, acc2[4] = {};
  float dp0 = 0.f, dp1 = 0.f;

  auto gstep = [&](int s_reg, float x0_reg, float x1_reg, int j, int cnt, f32x2* a) {
    int sj = __shfl(s_reg, j, 64);
    float xa = __shfl(x0_reg, j, 64);
    float xb = __shfl(x1_reg, j, 64);
    if (glane && j < cnt) {
      uint4 q = ((const uint4*)(h + (size_t)sj * HC))[f4];
      bf8_fma2(q, (f4 < HB) ? xa : xb, a);
    }
  };

  if (deg <= 64) {                  // fast path: single chunk, load once
    int i = beg + lane;
    bool in = i < end;
    int s = in ? colv[i] : 0;
    float2 a = in ? al_s[s] : make_float2(0.f, 0.f);
    float x0 = in ? __expf(leakyf(a.x + ad.x)) : 0.f;
    float x1 = in ? __expf(leakyf(a.y + ad.y)) : 0.f;
    dp0 = x0; dp1 = x1;
    for (int jj = 0; jj < deg; jj += 4 * ES) {
      gstep(s, x0, x1, jj + eslot, deg, acc);
      gstep(s, x0, x1, jj + ES + eslot, deg, acc2);
      gstep(s, x0, x1, jj + 2 * ES + eslot, deg, acc);
      gstep(s, x0, x1, jj + 3 * ES + eslot, deg, acc2);
    }
  } else {                          // general path (rare): chunked single pass
    for (int base = beg; base < end; base += 64) {
      int i = base + lane;
      bool in = i < end;
      int s = in ? colv[i] : 0;
      float2 a = in ? al_s[s] : make_float2(0.f, 0.f);
      float x0 = in ? __expf(leakyf(a.x + ad.x)) : 0.f;
      float x1 = in ? __expf(leakyf(a.y + ad.y)) : 0.f;
      dp0 += x0; dp1 += x1;
      int cnt = min(64, end - base);
      for (int jj = 0; jj < cnt; jj += 4 * ES) {
        gstep(s, x0, x1, jj + eslot, cnt, acc);
        gstep(s, x0, x1, jj + ES + eslot, cnt, acc2);
        gstep(s, x0, x1, jj + 2 * ES + eslot, cnt, acc);
        gstep(s, x0, x1, jj + 3 * ES + eslot, cnt, acc2);
      }
    }
  }

  // denominators
#pragma unroll
  for (int off = 1; off < 64; off <<= 1) {
    dp0 += __shfl_xor(dp0, off, 64);
    dp1 += __shfl_xor(dp1, off, 64);
  }
  float den0 = dp0 + xs0, den1 = dp1 + xs1;

  // self-loop message (slot 0 lanes)
  if (eslot == 0) {
    uint4 q = ((const uint4*)(h + (size_t)w * HC))[f4];
    bf8_fma2(q, (f4 < HB) ? xs0 : xs1, acc);
  }
#pragma unroll
  for (int i = 0; i < 4; ++i) acc[i] += acc2[i];

  // slot folds: sum per-slot partials into slot 0 (lanes < FL)
  auto fold = [&](int off, int lim) {
#pragma unroll
    for (int i = 0; i < 4; ++i) {
      float t0 = __shfl(acc[i][0], lane + off, 64);
      float t1 = __shfl(acc[i][1], lane + off, 64);
      if (lane < lim) { acc[i][0] += t0; acc[i][1] += t1; }
    }
  };
  if (ES == 4) {
    fold(2 * FL, 2 * FL);
    fold(FL, FL);
  } else {                 // ES == 6
    fold(3 * FL, 3 * FL);  // slots 0..2 += slots 3..5
    fold(FL, FL);          // slot 0 += slot 1
    fold(2 * FL, FL);      // slot 0 += slot 2
  }

  float inv0 = 1.f / (den0 + 1e-16f), inv1 = 1.f / (den1 + 1e-16f);
  if (CONCAT) {
    if (lane < FL) {
      float xx = (f4 < HB) ? inv0 : inv1;
      const float* bp = bias + f4 * 8;
      unsigned int pk[4];
#pragma unroll
      for (int i = 0; i < 4; ++i) {
        unsigned short lo = bf16r(eluf(acc[i][0] * xx + bp[2 * i]));
        unsigned short hi = bf16r(eluf(acc[i][1] * xx + bp[2 * i + 1]));
        pk[i] = (unsigned int)lo | ((unsigned int)hi << 16);
      }
      ((uint4*)(out + (size_t)w * OW + f4 * 8))[0] = make_uint4(pk[0], pk[1], pk[2], pk[3]);
    }
  } else {
    float p[8];
#pragma unroll
    for (int i = 0; i < 4; ++i) {
      p[2 * i]     = __shfl(acc[i][0], lane + HB, 64);
      p[2 * i + 1] = __shfl(acc[i][1], lane + HB, 64);
    }
    if (lane < HB) {
      const float* bp = bias + f4 * 8;
      unsigned int pk[4];
#pragma unroll
      for (int i = 0; i < 4; ++i) {
        float v0 = 0.5f * (acc[i][0] * inv0 + p[2 * i] * inv1) + bp[2 * i];
        float v1 = 0.5f * (acc[i][1] * inv0 + p[2 * i + 1] * inv1) + bp[2 * i + 1];
        pk[i] = (unsigned int)bf16r(eluf(v0)) | ((unsigned int)bf16r(eluf(v1)) << 16);
      }
      ((uint4*)(out + (size_t)w * OW + f4 * 8))[0] = make_uint4(pk[0], pk[1], pk[2], pk[3]);
    }
  }
}

// ---------------- order-mix (bf16 states in; bf16 or fp32 out) ----------------
template<int BF16OUT>
__global__ __launch_bounds__(256) void mixb_kernel(const unsigned short* __restrict__ sb,
    const float* __restrict__ Wm, const float* __restrict__ wf,
    void* __restrict__ out, int perU) {
  int i = blockIdx.x * blockDim.x + threadIdx.x;
  if (i >= perU) return;
  const unsigned int* sp = (const unsigned int*)sb;
  unsigned int u0 = sp[i];
  unsigned int u1 = sp[perU + i];
  unsigned int u2 = sp[2 * perU + i];
  float a0 = bflo(u0), a1 = bfhi(u0);
  float b0 = bflo(u1), b1 = bfhi(u1);
  float c0 = bflo(u2), c1 = bfhi(u2);
  float r0 = 0.f, r1 = 0.f;
#pragma unroll
  for (int j = 0; j < 3; ++j) {
    float w0 = Wm[j], w1 = Wm[3 + j], w2 = Wm[6 + j], wj = wf[j];
    r0 += wj * eluf(a0 * w0 + b0 * w1 + c0 * w2);
    r1 += wj * eluf(a1 * w0 + b1 * w1 + c1 * w2);
  }
  if (BF16OUT) {
    ((unsigned int*)out)[i] = (unsigned int)bf16r(r0) | ((unsigned int)bf16r(r1) << 16);
  } else {
    ((float2*)out)[i] = make_float2(r0, r1);
  }
}

// ---------------- log_softmax ----------------
__global__ __launch_bounds__(256) void log_softmax_kernel(const float* __restrict__ x,
    float* __restrict__ out, int N, int C) {
  int w = (blockIdx.x * blockDim.x + threadIdx.x) >> 6;
  int lane = threadIdx.x & 63;
  if (w >= N) return;
  float v = (lane < C) ? x[(size_t)w * C + lane] : -INFINITY;
  float mx = v;
#pragma unroll
  for (int off = 1; off < 64; off <<= 1) mx = fmaxf(mx, __shfl_xor(mx, off, 64));
  float ex = (lane < C) ? expf(v - mx) : 0.f;
  float s = ex;
#pragma unroll
  for (int off = 1; off < 64; off <<= 1) s += __shfl_xor(s, off, 64);
  if (lane < C) out[(size_t)w * C + lane] = v - mx - logf(s);
}

// ---------------------------------------------------------------------------
extern "C" void kernel_launch(void* const* d_in, const int* in_sizes, int n_in,
                              void* d_out, int out_size, void* d_ws, size_t ws_size,
                              hipStream_t stream) {
  const int F_IN = 500;
  const int N = in_sizes[0] / F_IN;     // 50000
  const int E = in_sizes[1] / 2;        // 800000
  const int HC0 = 128;
  const int HC1 = 80;
  const int C1 = 40;
  const int K0pad = 512, K1pad = 128;

  const float* x0 = (const float*)d_in[0];
  P3c adj;
  adj.p[0] = (const int*)d_in[1];
  adj.p[1] = (const int*)d_in[2];
  adj.p[2] = (const int*)d_in[3];
  P3f W0p, as0p, ad0p, b0p, W1p, as1p, ad1p, b1p;
  for (int o = 0; o < 3; ++o) {
    W0p.p[o]  = (const float*)d_in[4 + 4 * o + 0];
    as0p.p[o] = (const float*)d_in[4 + 4 * o + 1];
    ad0p.p[o] = (const float*)d_in[4 + 4 * o + 2];
    b0p.p[o]  = (const float*)d_in[4 + 4 * o + 3];
    W1p.p[o]  = (const float*)d_in[16 + 4 * o + 0];
    as1p.p[o] = (const float*)d_in[16 + 4 * o + 1];
    ad1p.p[o] = (const float*)d_in[16 + 4 * o + 2];
    b1p.p[o]  = (const float*)d_in[16 + 4 * o + 3];
  }
  const float* agg0W = (const float*)d_in[28];
  const float* agg0w = (const float*)d_in[29];
  const float* agg1W = (const float*)d_in[30];
  const float* agg1w = (const float*)d_in[31];

  // ---- workspace layout ----
  char* ws = (char*)d_ws;
  size_t off = 0;
  auto alloc = [&](size_t bytes) -> void* {
    off = (off + 255) & ~(size_t)255;
    void* p = ws + off;
    off += bytes;
    return p;
  };
  int* rowptrb = (int*)alloc((size_t)3 * (N + 1) * 4);
  int* colvb   = (int*)alloc((size_t)3 * E * 4);
  int* cntcur  = (int*)alloc((size_t)6 * N * 4);   // cnt[3N] then cur[3N]
  int* bsums   = (int*)alloc(3 * 64 * 4);
  unsigned short* x0b = (unsigned short*)alloc((size_t)N * K0pad * 2);    // bf16 x0
  unsigned short* hB  = (unsigned short*)alloc((size_t)3 * N * HC0 * 2);  // bf16 h
  unsigned short* stB = (unsigned short*)alloc((size_t)3 * N * HC0 * 2);  // bf16 states; block0 reused as bf16 x1
  float* x2 = (float*)alloc((size_t)N * C1 * 4);
  float2* alsB = (float2*)alloc((size_t)3 * N * 8);
  float2* aldB = (float2*)alloc((size_t)3 * N * 8);
  unsigned short* Bt0B = (unsigned short*)alloc((size_t)3 * HC0 * K0pad * 2);
  unsigned short* Bt1B = (unsigned short*)alloc((size_t)3 * HC1 * K1pad * 2);
  (void)ws_size;

  const int TB = 256;
  const int nbE = (E + TB - 1) / TB;
  const int nbN = (N + TB - 1) / TB;
  const int scanBlocks = (N + SCAN_TILE - 1) / SCAN_TILE;
  const int waveBlocks = (int)(((size_t)N * 64 + TB - 1) / TB);
  const int gemmBlocks = (N + GBM - 1) / GBM;

  // ---- conversions ----
  convA_kernel<<<(int)(((size_t)N * 64 + TB - 1) / TB), TB, 0, stream>>>(
      x0, x0b, N, F_IN, K0pad);
  conv_bt3_kernel<<<dim3((K0pad + 255) / 256, HC0, 3), TB, 0, stream>>>(W0p, Bt0B, F_IN, HC0, K0pad);
  conv_bt3_kernel<<<dim3((K1pad + 255) / 256, HC1, 3), TB, 0, stream>>>(W1p, Bt1B, HC0, HC1, K1pad);

  // ---- CSR, all 3 orders ----
  zero_int_kernel<<<(6 * N + TB - 1) / TB, TB, 0, stream>>>(cntcur, 6 * N);
  count3_kernel<<<dim3(nbE, 3), TB, 0, stream>>>(adj, cntcur, E, N);
  scan1_kernel<<<dim3(scanBlocks, 3), SCAN_T, 0, stream>>>(cntcur, rowptrb, bsums, N);
  scan2_kernel<<<1, 64, 0, stream>>>(bsums, scanBlocks, rowptrb, N);
  scan3_kernel<<<dim3(nbN, 3), TB, 0, stream>>>(rowptrb, bsums, N);
  fill3_kernel<<<dim3(nbE, 3), TB, 0, stream>>>(adj, rowptrb, cntcur + 3 * N, colvb, E, N);

  // ---- layer 0 (concat) ----
  mfma_gemm_kernel<8><<<dim3(gemmBlocks, 3), TB, 0, stream>>>(
      x0b, Bt0B, as0p, ad0p, hB, alsB, aldB, N, K0pad);
  gat_aggr4_kernel<64, 1><<<dim3(waveBlocks, 3), TB, 0, stream>>>(
      hB, alsB, aldB, rowptrb, colvb, b0p, stB, N, E);
  mixb_kernel<1><<<((N * HC0 / 2) + TB - 1) / TB, TB, 0, stream>>>(
      stB, agg0W, agg0w, stB, N * HC0 / 2);   // in-place bf16 x1 over state block 0

  // ---- layer 1 (mean over heads) ----
  mfma_gemm_kernel<5><<<dim3(gemmBlocks, 3), TB, 0, stream>>>(
      stB, Bt1B, as1p, ad1p, hB, alsB, aldB, N, K1pad);
  gat_aggr4_kernel<40, 0><<<dim3(waveBlocks, 3), TB, 0, stream>>>(
      hB, alsB, aldB, rowptrb, colvb, b1p, stB, N, E);
  mixb_kernel<0><<<((N * C1 / 2) + TB - 1) / TB, TB, 0, stream>>>(
      stB, agg1W, agg1w, x2, N * C1 / 2);

  log_softmax_kernel<<<waveBlocks, TB, 0, stream>>>(x2, (float*)d_out, N, C1);
}